// Round 1
// baseline (2922.116 us; speedup 1.0000x reference)
//
#include <hip/hip_runtime.h>

#define TPB 256

// ---- kernel 1: zero the two degree arrays (ws is poisoned each call) ----
__global__ void ewn_zero_kernel(float* __restrict__ deg, const int* __restrict__ pN) {
    int n2 = 2 * (*pN);
    for (int i = blockIdx.x * blockDim.x + threadIdx.x; i < n2;
         i += gridDim.x * blockDim.x) {
        deg[i] = 0.0f;
    }
}

// ---- kernel 2: scatter-add edge weights into out_deg[src], in_deg[dst] ----
__global__ void ewn_scatter_kernel(const float* __restrict__ w,
                                   const int* __restrict__ src,
                                   const int* __restrict__ dst,
                                   float* __restrict__ deg_out,
                                   float* __restrict__ deg_in,
                                   int E) {
    int i = blockIdx.x * blockDim.x + threadIdx.x;
    long long i4 = (long long)i * 4;
    if (i4 + 3 < E) {
        float4 wv = *(const float4*)(w + i4);
        int4  sv = *(const int4*)(src + i4);
        int4  dv = *(const int4*)(dst + i4);
        atomicAdd(&deg_out[sv.x], wv.x);
        atomicAdd(&deg_out[sv.y], wv.y);
        atomicAdd(&deg_out[sv.z], wv.z);
        atomicAdd(&deg_out[sv.w], wv.w);
        atomicAdd(&deg_in[dv.x], wv.x);
        atomicAdd(&deg_in[dv.y], wv.y);
        atomicAdd(&deg_in[dv.z], wv.z);
        atomicAdd(&deg_in[dv.w], wv.w);
    } else if (i4 < E) {
        for (long long j = i4; j < E; ++j) {
            float wj = w[j];
            atomicAdd(&deg_out[src[j]], wj);
            atomicAdd(&deg_in[dst[j]], wj);
        }
    }
}

// ---- kernel 3: deg -> 1/sqrt(deg), in place, over 2N entries ----
__global__ void ewn_norm_kernel(float* __restrict__ deg, const int* __restrict__ pN) {
    int n2 = 2 * (*pN);
    for (int i = blockIdx.x * blockDim.x + threadIdx.x; i < n2;
         i += gridDim.x * blockDim.x) {
        // precise 1/sqrtf (no fast-math): keeps absmax err ~1e-6
        deg[i] = 1.0f / sqrtf(deg[i]);
    }
}

// ---- kernel 4: out[e] = norm_out[src[e]] * norm_in[dst[e]] * w[e] ----
__global__ void ewn_gather_kernel(const float* __restrict__ w,
                                  const int* __restrict__ src,
                                  const int* __restrict__ dst,
                                  const float* __restrict__ norm_out,
                                  const float* __restrict__ norm_in,
                                  float* __restrict__ out,
                                  int E) {
    int i = blockIdx.x * blockDim.x + threadIdx.x;
    long long i4 = (long long)i * 4;
    if (i4 + 3 < E) {
        float4 wv = *(const float4*)(w + i4);
        int4  sv = *(const int4*)(src + i4);
        int4  dv = *(const int4*)(dst + i4);
        float4 ov;
        ov.x = norm_out[sv.x] * norm_in[dv.x] * wv.x;
        ov.y = norm_out[sv.y] * norm_in[dv.y] * wv.y;
        ov.z = norm_out[sv.z] * norm_in[dv.z] * wv.z;
        ov.w = norm_out[sv.w] * norm_in[dv.w] * wv.w;
        *(float4*)(out + i4) = ov;
    } else if (i4 < E) {
        for (long long j = i4; j < E; ++j) {
            out[j] = norm_out[src[j]] * norm_in[dst[j]] * w[j];
        }
    }
}

extern "C" void kernel_launch(void* const* d_in, const int* in_sizes, int n_in,
                              void* d_out, int out_size, void* d_ws, size_t ws_size,
                              hipStream_t stream) {
    const float* edge_weight = (const float*)d_in[0];
    const int*   src         = (const int*)d_in[1];
    const int*   dst         = (const int*)d_in[2];
    const int*   pN          = (const int*)d_in[3];  // 1-element device array
    float* out = (float*)d_out;
    const int E = in_sizes[0];

    // workspace layout: [0, N) = out_deg/out_norm, [N, 2N) = in_deg/in_norm
    // N is only known on device; we know ws holds >= 2*N floats per harness.
    float* deg = (float*)d_ws;
    // dst half pointer computed on device-known N? No — kernels take deg base
    // and pN; in/out halves are deg and deg + N read on device. To keep the
    // scatter kernel simple (it needs both base pointers), we pass deg and
    // deg + 100000 is NOT safe without knowing N on host. Instead the scatter
    // kernel indexes in_deg as deg[N + idx] via pN.
    // (Implemented below by passing deg twice with an on-device offset.)

    int nBlocksEdges = (E / 4 + TPB - 1) / TPB;

    ewn_zero_kernel<<<384, TPB, 0, stream>>>(deg, pN);
    ewn_scatter2_launch:;
    // scatter: in_deg base = deg + N, computed on device
    {
        // wrapper kernel computes in_deg = deg + *pN internally — see kernel
    }
    // Use a small adapter: pass pN so kernels offset internally.
    extern __global__ void ewn_scatter_off_kernel(const float*, const int*, const int*,
                                                  float*, const int*, int);
    // (defined below)
    ewn_scatter_off_kernel<<<nBlocksEdges, TPB, 0, stream>>>(edge_weight, src, dst, deg, pN, E);
    ewn_norm_kernel<<<384, TPB, 0, stream>>>(deg, pN);
    extern __global__ void ewn_gather_off_kernel(const float*, const int*, const int*,
                                                 const float*, const int*, float*, int);
    ewn_gather_off_kernel<<<nBlocksEdges, TPB, 0, stream>>>(edge_weight, src, dst, deg, pN, out, E);
}

// ---- offset variants: in_deg = deg + *pN (N only known on device) ----
__global__ void ewn_scatter_off_kernel(const float* __restrict__ w,
                                       const int* __restrict__ src,
                                       const int* __restrict__ dst,
                                       float* __restrict__ deg,
                                       const int* __restrict__ pN,
                                       int E) {
    const int N = *pN;
    float* deg_out = deg;
    float* deg_in  = deg + N;
    int i = blockIdx.x * blockDim.x + threadIdx.x;
    long long i4 = (long long)i * 4;
    if (i4 + 3 < E) {
        float4 wv = *(const float4*)(w + i4);
        int4  sv = *(const int4*)(src + i4);
        int4  dv = *(const int4*)(dst + i4);
        atomicAdd(&deg_out[sv.x], wv.x);
        atomicAdd(&deg_out[sv.y], wv.y);
        atomicAdd(&deg_out[sv.z], wv.z);
        atomicAdd(&deg_out[sv.w], wv.w);
        atomicAdd(&deg_in[dv.x], wv.x);
        atomicAdd(&deg_in[dv.y], wv.y);
        atomicAdd(&deg_in[dv.z], wv.z);
        atomicAdd(&deg_in[dv.w], wv.w);
    } else if (i4 < E) {
        for (long long j = i4; j < E; ++j) {
            float wj = w[j];
            atomicAdd(&deg_out[src[j]], wj);
            atomicAdd(&deg_in[dst[j]], wj);
        }
    }
}

__global__ void ewn_gather_off_kernel(const float* __restrict__ w,
                                      const int* __restrict__ src,
                                      const int* __restrict__ dst,
                                      const float* __restrict__ deg,
                                      const int* __restrict__ pN,
                                      float* __restrict__ out,
                                      int E) {
    const int N = *pN;
    const float* norm_out = deg;
    const float* norm_in  = deg + N;
    int i = blockIdx.x * blockDim.x + threadIdx.x;
    long long i4 = (long long)i * 4;
    if (i4 + 3 < E) {
        float4 wv = *(const float4*)(w + i4);
        int4  sv = *(const int4*)(src + i4);
        int4  dv = *(const int4*)(dst + i4);
        float4 ov;
        ov.x = norm_out[sv.x] * norm_in[dv.x] * wv.x;
        ov.y = norm_out[sv.y] * norm_in[dv.y] * wv.y;
        ov.z = norm_out[sv.z] * norm_in[dv.z] * wv.z;
        ov.w = norm_out[sv.w] * norm_in[dv.w] * wv.w;
        *(float4*)(out + i4) = ov;
    } else if (i4 < E) {
        for (long long j = i4; j < E; ++j) {
            out[j] = norm_out[src[j]] * norm_in[dst[j]] * w[j];
        }
    }
}

// Round 2
// 2877.370 us; speedup vs baseline: 1.0156x; 1.0156x over previous
//
#include <hip/hip_runtime.h>

#define TPB 256

__device__ __forceinline__ unsigned xcc_id() {
    unsigned v;
    asm volatile("s_getreg_b32 %0, hwreg(HW_REG_XCC_ID)" : "=s"(v));
    return v & 7u;
}

// replicas: R copies of [out_deg (N) | in_deg (N)] back to back in ws.
// R computed identically on device in every kernel: min(8, ws_floats/(2N)).
__device__ __forceinline__ int calc_R(unsigned long long ws_bytes, int N) {
    unsigned long long ws_floats = ws_bytes / 4ull;
    unsigned long long r = ws_floats / (unsigned long long)(2 * N);
    if (r > 8ull) r = 8ull;
    if (r < 1ull) r = 1ull;
    return (int)r;
}

// ---- kernel 1: zero R*2N floats of replica space ----
__global__ void ewn_zero_kernel(float* __restrict__ ws,
                                const int* __restrict__ pN,
                                unsigned long long ws_bytes) {
    int N = *pN;
    int R = calc_R(ws_bytes, N);
    long long total = (long long)R * 2 * N;
    for (long long i = blockIdx.x * (long long)blockDim.x + threadIdx.x; i < total;
         i += (long long)gridDim.x * blockDim.x) {
        ws[i] = 0.0f;
    }
}

// ---- kernel 2: scatter-add into per-XCD replica with workgroup-scope atomics ----
__global__ void ewn_scatter_kernel(const float* __restrict__ w,
                                   const int* __restrict__ src,
                                   const int* __restrict__ dst,
                                   float* __restrict__ ws,
                                   const int* __restrict__ pN,
                                   unsigned long long ws_bytes,
                                   int E) {
    const int N = *pN;
    const int R = calc_R(ws_bytes, N);
    const unsigned xcc = xcc_id();

    int i = blockIdx.x * blockDim.x + threadIdx.x;
    long long i4 = (long long)i * 4;

    if (R == 8) {
        // one replica per XCD: workgroup-scope atomics stay in local L2 (no sc1)
        float* deg_out = ws + (unsigned long long)xcc * 2ull * N;
        float* deg_in  = deg_out + N;
        if (i4 + 3 < E) {
            float4 wv = *(const float4*)(w + i4);
            int4  sv = *(const int4*)(src + i4);
            int4  dv = *(const int4*)(dst + i4);
            __hip_atomic_fetch_add(&deg_out[sv.x], wv.x, __ATOMIC_RELAXED, __HIP_MEMORY_SCOPE_WORKGROUP);
            __hip_atomic_fetch_add(&deg_out[sv.y], wv.y, __ATOMIC_RELAXED, __HIP_MEMORY_SCOPE_WORKGROUP);
            __hip_atomic_fetch_add(&deg_out[sv.z], wv.z, __ATOMIC_RELAXED, __HIP_MEMORY_SCOPE_WORKGROUP);
            __hip_atomic_fetch_add(&deg_out[sv.w], wv.w, __ATOMIC_RELAXED, __HIP_MEMORY_SCOPE_WORKGROUP);
            __hip_atomic_fetch_add(&deg_in[dv.x],  wv.x, __ATOMIC_RELAXED, __HIP_MEMORY_SCOPE_WORKGROUP);
            __hip_atomic_fetch_add(&deg_in[dv.y],  wv.y, __ATOMIC_RELAXED, __HIP_MEMORY_SCOPE_WORKGROUP);
            __hip_atomic_fetch_add(&deg_in[dv.z],  wv.z, __ATOMIC_RELAXED, __HIP_MEMORY_SCOPE_WORKGROUP);
            __hip_atomic_fetch_add(&deg_in[dv.w],  wv.w, __ATOMIC_RELAXED, __HIP_MEMORY_SCOPE_WORKGROUP);
        } else if (i4 < E) {
            for (long long j = i4; j < E; ++j) {
                float wj = w[j];
                __hip_atomic_fetch_add(&deg_out[src[j]], wj, __ATOMIC_RELAXED, __HIP_MEMORY_SCOPE_WORKGROUP);
                __hip_atomic_fetch_add(&deg_in[dst[j]],  wj, __ATOMIC_RELAXED, __HIP_MEMORY_SCOPE_WORKGROUP);
            }
        }
    } else {
        // fallback (ws too small for 8 replicas): device-scope atomics, always correct
        float* deg_out = ws + (unsigned long long)(xcc % (unsigned)R) * 2ull * N;
        float* deg_in  = deg_out + N;
        if (i4 + 3 < E) {
            float4 wv = *(const float4*)(w + i4);
            int4  sv = *(const int4*)(src + i4);
            int4  dv = *(const int4*)(dst + i4);
            atomicAdd(&deg_out[sv.x], wv.x);
            atomicAdd(&deg_out[sv.y], wv.y);
            atomicAdd(&deg_out[sv.z], wv.z);
            atomicAdd(&deg_out[sv.w], wv.w);
            atomicAdd(&deg_in[dv.x],  wv.x);
            atomicAdd(&deg_in[dv.y],  wv.y);
            atomicAdd(&deg_in[dv.z],  wv.z);
            atomicAdd(&deg_in[dv.w],  wv.w);
        } else if (i4 < E) {
            for (long long j = i4; j < E; ++j) {
                float wj = w[j];
                atomicAdd(&deg_out[src[j]], wj);
                atomicAdd(&deg_in[dst[j]],  wj);
            }
        }
    }
}

// ---- kernel 3: reduce R replicas + rsqrt, result into replica 0 ----
__global__ void ewn_reduce_norm_kernel(float* __restrict__ ws,
                                       const int* __restrict__ pN,
                                       unsigned long long ws_bytes) {
    int N = *pN;
    int R = calc_R(ws_bytes, N);
    long long n2 = 2ll * N;
    for (long long i = blockIdx.x * (long long)blockDim.x + threadIdx.x; i < n2;
         i += (long long)gridDim.x * blockDim.x) {
        float s = 0.0f;
        for (int r = 0; r < R; ++r) s += ws[(long long)r * n2 + i];
        ws[i] = 1.0f / sqrtf(s);   // precise rsqrt to stay under absmax threshold
    }
}

// ---- kernel 4: out[e] = norm_out[src[e]] * norm_in[dst[e]] * w[e] ----
__global__ void ewn_gather_kernel(const float* __restrict__ w,
                                  const int* __restrict__ src,
                                  const int* __restrict__ dst,
                                  const float* __restrict__ ws,
                                  const int* __restrict__ pN,
                                  float* __restrict__ out,
                                  int E) {
    const int N = *pN;
    const float* norm_out = ws;
    const float* norm_in  = ws + N;
    int i = blockIdx.x * blockDim.x + threadIdx.x;
    long long i4 = (long long)i * 4;
    if (i4 + 3 < E) {
        float4 wv = *(const float4*)(w + i4);
        int4  sv = *(const int4*)(src + i4);
        int4  dv = *(const int4*)(dst + i4);
        float4 ov;
        ov.x = norm_out[sv.x] * norm_in[dv.x] * wv.x;
        ov.y = norm_out[sv.y] * norm_in[dv.y] * wv.y;
        ov.z = norm_out[sv.z] * norm_in[dv.z] * wv.z;
        ov.w = norm_out[sv.w] * norm_in[dv.w] * wv.w;
        *(float4*)(out + i4) = ov;
    } else if (i4 < E) {
        for (long long j = i4; j < E; ++j) {
            out[j] = norm_out[src[j]] * norm_in[dst[j]] * w[j];
        }
    }
}

extern "C" void kernel_launch(void* const* d_in, const int* in_sizes, int n_in,
                              void* d_out, int out_size, void* d_ws, size_t ws_size,
                              hipStream_t stream) {
    const float* edge_weight = (const float*)d_in[0];
    const int*   src         = (const int*)d_in[1];
    const int*   dst         = (const int*)d_in[2];
    const int*   pN          = (const int*)d_in[3];  // 1-element device array
    float* out = (float*)d_out;
    const int E = in_sizes[0];
    float* ws = (float*)d_ws;
    unsigned long long wsb = (unsigned long long)ws_size;

    int nBlocksEdges = (E / 4 + TPB - 1) / TPB;

    ewn_zero_kernel<<<1024, TPB, 0, stream>>>(ws, pN, wsb);
    ewn_scatter_kernel<<<nBlocksEdges, TPB, 0, stream>>>(edge_weight, src, dst, ws, pN, wsb, E);
    ewn_reduce_norm_kernel<<<1024, TPB, 0, stream>>>(ws, pN, wsb);
    ewn_gather_kernel<<<nBlocksEdges, TPB, 0, stream>>>(edge_weight, src, dst, ws, pN, out, E);
}